// Round 5
// baseline (1070.775 us; speedup 1.0000x reference)
//
#include <hip/hip_runtime.h>
#include <stdint.h>

#define D 128
#define H 256
#define LSTR 264   // LDS row stride in shorts (padded vs 256 to break bank conflicts)

typedef short s8v __attribute__((ext_vector_type(8)));   // 8 x bf16 fragment (4 VGPRs)
typedef float f4v __attribute__((ext_vector_type(4)));   // 4 x f32 accumulator

__device__ __forceinline__ short f2bf(float f){
  union { float f; unsigned u; } v; v.f = f;
  unsigned r = v.u + 0x7fffu + ((v.u >> 16) & 1u);       // round-to-nearest-even
  return (short)(r >> 16);
}

// ---- prep: swizzle W1,W2 into bf16 MFMA B-fragment order; zero stats ----
__global__ void k_prep(const float* __restrict__ W1, const float* __restrict__ W2,
                       short* __restrict__ W1s, short* __restrict__ W2s,
                       float* __restrict__ st1, float* __restrict__ st2){
  int t = blockIdx.x*256 + threadIdx.x;
  if (t < 32768){                               // W1 [H=256][D=128], 16 jt x 4 kt
    int j = t & 7, lane = (t>>3) & 63, kt = (t>>9) & 3, jt = t>>11;
    int col = jt*16 + (lane & 15);
    int k   = kt*32 + (lane>>4)*8 + j;
    W1s[t] = f2bf(W1[col*D + k]);
  } else if (t < 65536){                        // W2 [D=128][H=256], 8 jt x 8 kt
    int u = t - 32768;
    int j = u & 7, lane = (u>>3) & 63, kt = (u>>9) & 7, jt = u>>12;
    int col = jt*16 + (lane & 15);
    int k   = kt*32 + (lane>>4)*8 + j;
    W2s[u] = f2bf(W2[col*H + k]);
  } else if (t < 71680){                        // zero stats: 8 shadows sum/sumsq
    int u = t - 65536;
    if (u < 8*2*H) st1[u] = 0.f;
    else st2[u - 8*2*H] = 0.f;                  // 8*2*D entries
  }
}

// ---- CSR scan, single block: offsets/cursor = exclusive scan of rint(deg).
//      Replaces scanA+scanB+scanC (3 launches -> 1); counts array deleted. ----
__global__ void k_scan(const float* __restrict__ deg, int* __restrict__ offsets,
                       int* __restrict__ cursor, int N_){
  __shared__ int part[1024];
  int t = threadIdx.x;
  int C = (N_ + 1023) >> 10;                    // contiguous chunk per thread
  int lo = t*C, hi = min(N_, lo + C);
  int s = 0;
  for (int i = lo; i < hi; i++) s += (int)(deg[i] + 0.5f);
  part[t] = s;
  __syncthreads();
  for (int o = 1; o < 1024; o <<= 1){           // Hillis-Steele inclusive scan
    int u = (t >= o) ? part[t-o] : 0;
    __syncthreads();
    part[t] += u;
    __syncthreads();
  }
  int pos = part[t] - s;                        // exclusive prefix of this chunk
  for (int i = lo; i < hi; i++){
    offsets[i] = pos; cursor[i] = pos;
    pos += (int)(deg[i] + 0.5f);                // deg chunk is L2-hot on re-read
  }
  if (t == 1023) offsets[N_] = part[t];
}

// ---- CSR fill: entry = (e<<1)|side, side=1 => at src ----
__global__ void k_fill(const int* __restrict__ src, const int* __restrict__ dst,
                       int* __restrict__ cursor, int* __restrict__ entries, int E_){
  int e = blockIdx.x*256 + threadIdx.x;
  if (e >= E_) return;
  int p = atomicAdd(&cursor[src[e]], 1);
  entries[p] = (e<<1) | 1;
  int q = atomicAdd(&cursor[dst[e]], 1);
  entries[q] = (e<<1);
}

// ---- gather: h[n] = (1+eps)*x[n] + sum_inc( x[other] + ea[e] ). One wave/node. ----
__global__ void k_gather(const float* __restrict__ x, const float* __restrict__ ea,
                         const int* __restrict__ src, const int* __restrict__ dst,
                         const int* __restrict__ offsets, const int* __restrict__ entries,
                         const float* __restrict__ eps, float* __restrict__ h, int N_){
  int n = (blockIdx.x*256 + threadIdx.x) >> 6;
  int lane = threadIdx.x & 63;
  if (n >= N_) return;
  int lo = offsets[n], hi = offsets[n+1];
  float2 xr = ((const float2*)(x + (size_t)n*D))[lane];
  float sc = 1.0f + eps[0];
  float ax = sc*xr.x, ay = sc*xr.y;
  for (int base = lo; base < hi; base += 64){
    int cnt = min(64, hi - base);
    int ent = 0, oth = 0;
    if (lane < cnt){
      ent = entries[base + lane];
      int e = ent >> 1;
      oth = (ent & 1) ? dst[e] : src[e];
    }
    int j = 0;
    for (; j+3 < cnt; j += 4){                  // 4-way unroll: 8 row loads in flight
      int e0 = __shfl(ent, j)   >> 1, o0 = __shfl(oth, j);
      int e1 = __shfl(ent, j+1) >> 1, o1 = __shfl(oth, j+1);
      int e2 = __shfl(ent, j+2) >> 1, o2 = __shfl(oth, j+2);
      int e3 = __shfl(ent, j+3) >> 1, o3 = __shfl(oth, j+3);
      float2 m0 = ((const float2*)(ea + (size_t)e0*D))[lane];
      float2 x0 = ((const float2*)(x  + (size_t)o0*D))[lane];
      float2 m1 = ((const float2*)(ea + (size_t)e1*D))[lane];
      float2 x1 = ((const float2*)(x  + (size_t)o1*D))[lane];
      float2 m2 = ((const float2*)(ea + (size_t)e2*D))[lane];
      float2 x2 = ((const float2*)(x  + (size_t)o2*D))[lane];
      float2 m3 = ((const float2*)(ea + (size_t)e3*D))[lane];
      float2 x3 = ((const float2*)(x  + (size_t)o3*D))[lane];
      ax += (m0.x + x0.x) + (m1.x + x1.x) + (m2.x + x2.x) + (m3.x + x3.x);
      ay += (m0.y + x0.y) + (m1.y + x1.y) + (m2.y + x2.y) + (m3.y + x3.y);
    }
    for (; j < cnt; j++){
      int e0 = __shfl(ent, j) >> 1, o0 = __shfl(oth, j);
      float2 m0 = ((const float2*)(ea + (size_t)e0*D))[lane];
      float2 x0 = ((const float2*)(x  + (size_t)o0*D))[lane];
      ax += m0.x + x0.x;
      ay += m0.y + x0.y;
    }
  }
  float2 o; o.x = ax; o.y = ay;
  ((float2*)(h + (size_t)n*D))[lane] = o;
}

// ---- GEMM1 stats-only, grid-stride + LDS stats accumulation:
//      global atomics cut ~6x (one flush per block into 8 shadows) ----
__launch_bounds__(256)
__global__ void k_gemm1(const float* __restrict__ h, const short* __restrict__ W1s,
                        float* __restrict__ st1, int nW){
  __shared__ float s1Acc[2*H];
  for (int u = threadIdx.x; u < 2*H; u += 256) s1Acc[u] = 0.f;
  __syncthreads();
  int lane = threadIdx.x & 63;
  int mrow = lane & 15, kg = lane >> 4;
  const s8v* Bf = (const s8v*)W1s;
  for (int wid = blockIdx.x*4 + (threadIdx.x>>6); wid < nW; wid += 2048){
    const float* hrow = h + (size_t)(wid*16 + mrow)*D + kg*8;
    s8v af[4];
#pragma unroll
    for (int kt=0; kt<4; kt++){
      float4 v0 = *(const float4*)(hrow + kt*32);
      float4 v1 = *(const float4*)(hrow + kt*32 + 4);
      s8v a;
      a[0]=f2bf(v0.x); a[1]=f2bf(v0.y); a[2]=f2bf(v0.z); a[3]=f2bf(v0.w);
      a[4]=f2bf(v1.x); a[5]=f2bf(v1.y); a[6]=f2bf(v1.z); a[7]=f2bf(v1.w);
      af[kt] = a;
    }
#pragma unroll
    for (int jt=0; jt<16; jt++){
      f4v acc = {0.f,0.f,0.f,0.f};
#pragma unroll
      for (int kt=0; kt<4; kt++)
        acc = __builtin_amdgcn_mfma_f32_16x16x32_bf16(af[kt], Bf[(jt*4+kt)*64 + lane], acc, 0, 0, 0);
      float s = acc[0]+acc[1]+acc[2]+acc[3];
      float q = acc[0]*acc[0]+acc[1]*acc[1]+acc[2]*acc[2]+acc[3]*acc[3];
      s += __shfl_xor(s,16); s += __shfl_xor(s,32);
      q += __shfl_xor(q,16); q += __shfl_xor(q,32);
      if (lane < 16){                            // 16 distinct banks: conflict-free
        atomicAdd(&s1Acc[jt*16 + lane], s);
        atomicAdd(&s1Acc[H + jt*16 + lane], q);
      }
    }
  }
  __syncthreads();
  for (int u = threadIdx.x; u < 2*H; u += 256)
    atomicAdd(&st1[(blockIdx.x & 7)*(2*H) + u], s1Acc[u]);
}

__global__ void k_fin1(const float* __restrict__ st1, const float* __restrict__ g,
                       const float* __restrict__ b, float* __restrict__ a,
                       float* __restrict__ c, float invN){
  int j = threadIdx.x;                          // H threads
  float s=0.f, q=0.f;
#pragma unroll
  for (int i=0;i<8;i++){ s += st1[i*(2*H) + j]; q += st1[i*(2*H) + H + j]; }
  float mu = s*invN;
  float var = q*invN - mu*mu;
  float rs = rsqrtf(var + 1e-5f);
  float aa = g[j]*rs;
  a[j] = aa; c[j] = b[j] - mu*aa;
}

// ---- GEMM2 fused, grid-stride + LDS stats: recompute Y1 tile, BN1+ReLU,
//      LDS transpose, second MFMA chain, Y2 overwrites own h rows, BN2 stats.
//      NOTE: h and Y2 alias (both = d_out) -> no __restrict__ on them. ----
__launch_bounds__(256)
__global__ void k_gemm2(const float* h, const short* __restrict__ W1s,
                        const short* __restrict__ W2s,
                        const float* __restrict__ a1, const float* __restrict__ c1,
                        float* Y2, float* __restrict__ st2, int nW){
  __shared__ short P[4*16*LSTR];                // 33792 B: per-wave 16x256 bf16 tile
  __shared__ float s2Acc[2*D];
  for (int u = threadIdx.x; u < 2*D; u += 256) s2Acc[u] = 0.f;
  __syncthreads();
  int wib  = threadIdx.x >> 6;
  int lane = threadIdx.x & 63;
  int mrow = lane & 15, kg = lane >> 4;
  short* Pw = P + wib*16*LSTR;
  const s8v* B1 = (const s8v*)W1s;
  const s8v* B2 = (const s8v*)W2s;

  for (int wid = blockIdx.x*4 + wib; wid < nW; wid += 2048){
    int r0 = wid*16;
    const float* hrow = h + (size_t)(r0 + mrow)*D + kg*8;
    s8v af[4];
#pragma unroll
    for (int kt=0; kt<4; kt++){
      float4 v0 = *(const float4*)(hrow + kt*32);
      float4 v1 = *(const float4*)(hrow + kt*32 + 4);
      s8v a;
      a[0]=f2bf(v0.x); a[1]=f2bf(v0.y); a[2]=f2bf(v0.z); a[3]=f2bf(v0.w);
      a[4]=f2bf(v1.x); a[5]=f2bf(v1.y); a[6]=f2bf(v1.z); a[7]=f2bf(v1.w);
      af[kt] = a;
    }
#pragma unroll
    for (int jt=0; jt<16; jt++){
      f4v acc = {0.f,0.f,0.f,0.f};
#pragma unroll
      for (int kt=0; kt<4; kt++)
        acc = __builtin_amdgcn_mfma_f32_16x16x32_bf16(af[kt], B1[(jt*4+kt)*64 + lane], acc, 0, 0, 0);
      int col = jt*16 + mrow;
      float a = a1[col], c = c1[col];
#pragma unroll
      for (int r=0; r<4; r++){
        float e = fmaxf(acc[r]*a + c, 0.f);
        Pw[(kg*4 + r)*LSTR + col] = f2bf(e);    // per-wave LDS region: in-wave dep only
      }
    }
    s8v af2[8];
#pragma unroll
    for (int k2=0; k2<8; k2++)
      af2[k2] = *(const s8v*)(Pw + mrow*LSTR + k2*32 + kg*8);
#pragma unroll
    for (int jt=0; jt<8; jt++){
      f4v acc = {0.f,0.f,0.f,0.f};
#pragma unroll
      for (int k2=0; k2<8; k2++)
        acc = __builtin_amdgcn_mfma_f32_16x16x32_bf16(af2[k2], B2[(jt*8+k2)*64 + lane], acc, 0, 0, 0);
      float s = acc[0]+acc[1]+acc[2]+acc[3];
      float q = acc[0]*acc[0]+acc[1]*acc[1]+acc[2]*acc[2]+acc[3]*acc[3];
#pragma unroll
      for (int r=0; r<4; r++){
        int row = r0 + kg*4 + r;
        Y2[(size_t)row*D + jt*16 + mrow] = acc[r];
      }
      s += __shfl_xor(s,16); s += __shfl_xor(s,32);
      q += __shfl_xor(q,16); q += __shfl_xor(q,32);
      if (lane < 16){
        atomicAdd(&s2Acc[jt*16 + lane], s);
        atomicAdd(&s2Acc[D + jt*16 + lane], q);
      }
    }
  }
  __syncthreads();
  for (int u = threadIdx.x; u < 2*D; u += 256)
    atomicAdd(&st2[(blockIdx.x & 7)*(2*D) + u], s2Acc[u]);
}

__global__ void k_fin2(const float* __restrict__ st2, const float* __restrict__ g,
                       const float* __restrict__ b, float* __restrict__ a,
                       float* __restrict__ c, float invN){
  int j = threadIdx.x;                          // D threads
  float s=0.f, q=0.f;
#pragma unroll
  for (int i=0;i<8;i++){ s += st2[i*(2*D) + j]; q += st2[i*(2*D) + D + j]; }
  float mu = s*invN;
  float var = q*invN - mu*mu;
  float rs = rsqrtf(var + 1e-5f);
  float aa = g[j]*rs;
  a[j] = aa; c[j] = b[j] - mu*aa;
}

// ---- out = relu(Y2*a2 + c2), in place on d_out ----
__global__ void k_final(const float* __restrict__ Y2, const float* __restrict__ a2,
                        const float* __restrict__ c2, float* __restrict__ out, int total4){
  int t = blockIdx.x*256 + threadIdx.x;
  if (t >= total4) return;
  int d4 = t & 31;
  float4 v = ((const float4*)Y2)[t];
  float4 A = ((const float4*)a2)[d4];
  float4 C = ((const float4*)c2)[d4];
  float4 o;
  o.x = fmaxf(v.x*A.x + C.x, 0.f);
  o.y = fmaxf(v.y*A.y + C.y, 0.f);
  o.z = fmaxf(v.z*A.z + C.z, 0.f);
  o.w = fmaxf(v.w*A.w + C.w, 0.f);
  ((float4*)out)[t] = o;
}

extern "C" void kernel_launch(void* const* d_in, const int* in_sizes, int n_in,
                              void* d_out, int out_size, void* d_ws, size_t ws_size,
                              hipStream_t stream){
  const float* x   = (const float*)d_in[0];
  const float* ea  = (const float*)d_in[1];
  const float* deg = (const float*)d_in[2];
  const float* eps = (const float*)d_in[3];
  const float* W1  = (const float*)d_in[4];
  const float* g1  = (const float*)d_in[5];
  const float* b1  = (const float*)d_in[6];
  const float* W2  = (const float*)d_in[7];
  const float* g2  = (const float*)d_in[8];
  const float* b2  = (const float*)d_in[9];
  const int* src   = (const int*)d_in[10];
  const int* dst   = (const int*)d_in[11];
  float* out = (float*)d_out;

  int N = in_sizes[2];
  int E = in_sizes[10];

  // workspace: ~5.7 MB (weights, stats, CSR; counts array deleted)
  char* w = (char*)d_ws;
  size_t off = 0;
  short* W1s = (short*)(w + off); off += (size_t)H*D*2;   // 64 KB swizzled bf16
  short* W2s = (short*)(w + off); off += (size_t)D*H*2;   // 64 KB
  float* st1 = (float*)(w + off); off += 8*2*H*4;         // 16 KB shadow sum/sumsq
  float* st2 = (float*)(w + off); off += 8*2*D*4;         // 8 KB
  float* a1  = (float*)(w + off); off += H*4;
  float* c1  = (float*)(w + off); off += H*4;
  float* a2  = (float*)(w + off); off += D*4;
  float* c2  = (float*)(w + off); off += D*4;
  int* offsets = (int*)(w + off); off += (size_t)(N+1)*4; // 400 KB
  int* cursor  = (int*)(w + off); off += (size_t)N*4;     // 400 KB
  int* entries = (int*)(w + off); off += (size_t)2*E*4;   // 4.8 MB

  float* h = out;                                         // [N,128] staging in d_out

  hipLaunchKernelGGL(k_prep, dim3(280), dim3(256), 0, stream,
                     W1, W2, W1s, W2s, st1, st2);
  hipLaunchKernelGGL(k_scan, dim3(1), dim3(1024), 0, stream, deg, offsets, cursor, N);
  int eb = (E + 255)/256;
  hipLaunchKernelGGL(k_fill, dim3(eb), dim3(256), 0, stream, src, dst, cursor, entries, E);
  hipLaunchKernelGGL(k_gather, dim3((N+3)/4), dim3(256), 0, stream,
                     x, ea, src, dst, offsets, entries, eps, h, N);
  int nW = (N + 15)/16;
  hipLaunchKernelGGL(k_gemm1, dim3(512), dim3(256), 0, stream, h, W1s, st1, nW);
  hipLaunchKernelGGL(k_fin1, dim3(1), dim3(H), 0, stream, st1, g1, b1, a1, c1, 1.0f/(float)N);
  hipLaunchKernelGGL(k_gemm2, dim3(512), dim3(256), 0, stream, h, W1s, W2s, a1, c1, h, st2, nW);
  hipLaunchKernelGGL(k_fin2, dim3(1), dim3(D), 0, stream, st2, g2, b2, a2, c2, 1.0f/(float)N);
  int total4 = N*(D/4);
  hipLaunchKernelGGL(k_final, dim3((total4+255)/256), dim3(256), 0, stream, h, a2, c2, out, total4);
}